// Round 1
// 57.524 us; speedup vs baseline: 1.0105x; 1.0105x over previous
//
#include <hip/hip_runtime.h>
#include <math.h>

#define NB 81
#define NW 140

struct alignas(16) U2 { unsigned long long x, y; };
struct F2 { float d, e; };

struct Tables {
    U2 m[NW];              // window membership masks: .x = cells 0..63, .y = cells 64..80
    unsigned cw32[NB][8];  // per-cell window ids, 4 u8 per u32 (20 ids in words 0..4); 0x8C=140 pad
};

constexpr Tables make_tables() {
    Tables t{};
    for (int a = 0; a < NB; ++a)
        for (int j = 0; j < 8; ++j) t.cw32[a][j] = 0x8C8C8C8Cu;  // 140 = dummy window (delta 0)
    int cnt[NB] = {};
    const int DR[4] = {0, 1, 1, 1};
    const int DC[4] = {1, 0, 1, -1};
    int w = 0;
    for (int d = 0; d < 4; ++d)
        for (int r = 0; r < 9; ++r)
            for (int c = 0; c < 9; ++c) {
                const int er = r + 4 * DR[d], ec = c + 4 * DC[d];
                if (er < 0 || er > 8 || ec < 0 || ec > 8) continue;
                unsigned long long lo = 0, hi = 0;
                for (int k = 0; k < 5; ++k) {
                    const int cell = (r + k * DR[d]) * 9 + (c + k * DC[d]);
                    if (cell < 64) lo |= 1ull << cell;
                    else           hi |= 1ull << (cell - 64);
                    const int i = cnt[cell]++;
                    t.cw32[cell][i >> 2] &= ~(0xFFu << (8 * (i & 3)));
                    t.cw32[cell][i >> 2] |= (unsigned)w << (8 * (i & 3));
                }
                t.m[w].x = lo; t.m[w].y = hi; ++w;
            }
    return t;
}

// Combined (oc,pc) -> {per-cell delta, ev contribution} table, stride 8 for cheap addressing.
struct WTab { F2 v[48]; };
constexpr WTab make_wt() {
    WTab t{};
    float PT[6] = {0.f, 5.f, 50.f, 500.f, 5000.f, 100000.f};
    for (int oc = 0; oc < 6; ++oc)
        for (int pc = 0; pc < 6; ++pc) {
            float d = 0.f, e = 0.f;
            if (oc == 0)      { d = (pc < 5) ? (PT[pc + 1] - PT[pc]) : 0.f; e = PT[pc]; }
            else if (pc == 0) { d = PT[oc]; e = -PT[oc]; }
            if (pc == 4) d = 1.0e9f;  // win marker; only empty cells can gather an oc==0,pc==4 window
            t.v[oc * 8 + pc] = F2{d, e};
        }
    return t;
}

__device__ __constant__ Tables TAB = make_tables();
__device__ __constant__ WTab WT = make_wt();

__device__ __forceinline__ float wave_sum(float v) {
#pragma unroll
    for (int m = 1; m < 64; m <<= 1) v += __shfl_xor(v, m, 64);
    return v;
}
__device__ __forceinline__ float wave_max(float v) {
#pragma unroll
    for (int m = 1; m < 64; m <<= 1) v = fmaxf(v, __shfl_xor(v, m, 64));
    return v;
}

__global__ __launch_bounds__(256) void heur9_kernel(const float* __restrict__ boards,
                                                    const int* __restrict__ cur,
                                                    float* __restrict__ out, int B) {
    __shared__ float sD[4][NW + 1];
    const int wave = threadIdx.x >> 6;
    const int lane = threadIdx.x & 63;
    const int b = (blockIdx.x << 2) | wave;   // grid = B/4 exactly
    float* dl = sD[wave];
    const float* brd = boards + b * NB;

    const float pf = (float)cur[b];
    const float of = 3.0f - pf;
    const float v1 = brd[lane];
    const float v2 = (lane < NB - 64) ? brd[lane + 64] : -1.0f;  // -1 matches neither player

    // Occupancy bitboards via wave ballot (uniform across wave).
    const unsigned long long p_lo = __ballot(v1 == pf);
    const unsigned long long p_hi = __ballot(v2 == pf);
    const unsigned long long o_lo = __ballot(v1 == of);
    const unsigned long long o_hi = __ballot(v2 == of);
    const unsigned long long e_lo = ~(p_lo | o_lo);
    const unsigned long long e_hi = ~(p_hi | o_hi);  // only low 17 bits meaningful

    // Window pass: 3 fixed strides, one 16B mask load + one 8B table load per window.
    float evp = 0.f;
    const U2 m0 = TAB.m[lane];
    const U2 m1 = TAB.m[lane + 64];   // lane+64 <= 127 < 140
    {
        const int pc = __popcll(p_lo & m0.x) + __popcll(p_hi & m0.y);
        const int oc = __popcll(o_lo & m0.x) + __popcll(o_hi & m0.y);
        const F2 tt = WT.v[(oc << 3) + pc];
        evp += tt.e;
        dl[lane] = tt.d;
    }
    {
        const int pc = __popcll(p_lo & m1.x) + __popcll(p_hi & m1.y);
        const int oc = __popcll(o_lo & m1.x) + __popcll(o_hi & m1.y);
        const F2 tt = WT.v[(oc << 3) + pc];
        evp += tt.e;
        dl[lane + 64] = tt.d;
    }
    if (lane < NW - 128) {            // lanes 0..11
        const U2 m2 = TAB.m[lane + 128];
        const int pc = __popcll(p_lo & m2.x) + __popcll(p_hi & m2.y);
        const int oc = __popcll(o_lo & m2.x) + __popcll(o_hi & m2.y);
        const F2 tt = WT.v[(oc << 3) + pc];
        evp += tt.e;
        dl[lane + 128] = tt.d;
    }
    if (lane == 0) dl[NW] = 0.f;      // dummy window for table padding

    const float ev = wave_sum(evp);

    // sD[wave] is private to this wave: a wave-local LDS drain replaces __syncthreads().
    // DS ops of one wave complete in order; lgkmcnt(0) guarantees all lanes' writes visible.
    asm volatile("s_waitcnt lgkmcnt(0)" ::: "memory");
    __builtin_amdgcn_sched_barrier(0);

    // Cell pass: gather <=20 per-window deltas via constexpr index table (32B-aligned rows).
    float sd1 = 0.f, sd2 = 0.f;
#pragma unroll
    for (int j = 0; j < 5; ++j) {
        const unsigned q = TAB.cw32[lane][j];
        sd1 += dl[q & 255] + dl[(q >> 8) & 255] + dl[(q >> 16) & 255] + dl[q >> 24];
    }
    if (lane < NB - 64) {
#pragma unroll
        for (int j = 0; j < 5; ++j) {
            const unsigned q = TAB.cw32[lane + 64][j];
            sd2 += dl[q & 255] + dl[(q >> 8) & 255] + dl[(q >> 16) & 255] + dl[q >> 24];
        }
    }
    const bool emp1 = (e_lo >> lane) & 1ull;
    const bool emp2 = (lane < NB - 64) && ((e_hi >> lane) & 1ull);
    float l1 = emp1 ? (sd1 >= 5.0e8f ? 100000.f : ev + sd1) : -1000000.f;
    float l2 = (lane < NB - 64)
                 ? (emp2 ? (sd2 >= 5.0e8f ? 100000.f : ev + sd2) : -1000000.f)
                 : -INFINITY;
    l1 *= 0.03f; l2 *= 0.03f;

    const float m = wave_max(fmaxf(l1, l2));
    const float e1 = __expf(l1 - m);
    const float e2 = (lane < NB - 64) ? __expf(l2 - m) : 0.f;
    const float inv = 1.0f / wave_sum(e1 + e2);

    out[b * NB + lane] = e1 * inv;
    if (lane < NB - 64) out[b * NB + lane + 64] = e2 * inv;
    if (lane == 0) {
        const float v = tanhf(ev * (1.f / 3000.f));
        out[B * NB + b] = fminf(fmaxf(v, -0.95f), 0.95f);
    }
}

extern "C" void kernel_launch(void* const* d_in, const int* in_sizes, int n_in,
                              void* d_out, int out_size, void* d_ws, size_t ws_size,
                              hipStream_t stream) {
    const float* boards = (const float*)d_in[0];
    const int* cur = (const int*)d_in[1];
    float* out = (float*)d_out;
    const int B = in_sizes[0] / NB;   // 2048
    heur9_kernel<<<B / 4, 256, 0, stream>>>(boards, cur, out, B);
}

// Round 2
// 56.799 us; speedup vs baseline: 1.0234x; 1.0128x over previous
//
#include <hip/hip_runtime.h>
#include <math.h>

#define NB 81
#define NW 140

struct alignas(16) U2 { unsigned long long x, y; };
struct F2 { float d, e; };

struct Tables {
    U2 m[NW];              // window membership masks: .x = cells 0..63, .y = cells 64..80
    unsigned cw32[NB][8];  // per-cell window ids, 4 u8 per u32 (20 ids in words 0..4); 0x8C=140 pad
};

constexpr Tables make_tables() {
    Tables t{};
    for (int a = 0; a < NB; ++a)
        for (int j = 0; j < 8; ++j) t.cw32[a][j] = 0x8C8C8C8Cu;  // 140 = dummy window (delta 0)
    int cnt[NB] = {};
    const int DR[4] = {0, 1, 1, 1};
    const int DC[4] = {1, 0, 1, -1};
    int w = 0;
    for (int d = 0; d < 4; ++d)
        for (int r = 0; r < 9; ++r)
            for (int c = 0; c < 9; ++c) {
                const int er = r + 4 * DR[d], ec = c + 4 * DC[d];
                if (er < 0 || er > 8 || ec < 0 || ec > 8) continue;
                unsigned long long lo = 0, hi = 0;
                for (int k = 0; k < 5; ++k) {
                    const int cell = (r + k * DR[d]) * 9 + (c + k * DC[d]);
                    if (cell < 64) lo |= 1ull << cell;
                    else           hi |= 1ull << (cell - 64);
                    const int i = cnt[cell]++;
                    t.cw32[cell][i >> 2] &= ~(0xFFu << (8 * (i & 3)));
                    t.cw32[cell][i >> 2] |= (unsigned)w << (8 * (i & 3));
                }
                t.m[w].x = lo; t.m[w].y = hi; ++w;
            }
    return t;
}

// Combined (oc,pc) -> {per-cell delta, ev contribution} table, stride 8 for cheap addressing.
struct WTab { F2 v[48]; };
constexpr WTab make_wt() {
    WTab t{};
    float PT[6] = {0.f, 5.f, 50.f, 500.f, 5000.f, 100000.f};
    for (int oc = 0; oc < 6; ++oc)
        for (int pc = 0; pc < 6; ++pc) {
            float d = 0.f, e = 0.f;
            if (oc == 0)      { d = (pc < 5) ? (PT[pc + 1] - PT[pc]) : 0.f; e = PT[pc]; }
            else if (pc == 0) { d = PT[oc]; e = -PT[oc]; }
            if (pc == 4) d = 1.0e9f;  // win marker; only empty cells can gather an oc==0,pc==4 window
            t.v[oc * 8 + pc] = F2{d, e};
        }
    return t;
}

__device__ __constant__ Tables TAB = make_tables();
__device__ __constant__ WTab WT = make_wt();

// DPP full-wave reductions: row_shr 1/2/4/8 + row_bcast15(rows 1,3) + row_bcast31(rows 2,3);
// lane 63 holds the result, broadcast via readlane. ~6 VALU ops vs 6 ds_swizzle (~30-40cy each).
#define DPP_ADD(v, ctrl, rmask)                                                              \
    v += __int_as_float(                                                                     \
        __builtin_amdgcn_update_dpp(0, __float_as_int(v), ctrl, rmask, 0xF, true));
#define DPP_MAX(v, ctrl, rmask)                                                              \
    {                                                                                        \
        const int _x = __builtin_amdgcn_update_dpp(__float_as_int(v), __float_as_int(v),     \
                                                   ctrl, rmask, 0xF, false);                 \
        v = fmaxf(v, __int_as_float(_x));                                                    \
    }

__device__ __forceinline__ float wave_red_sum(float v) {
    DPP_ADD(v, 0x111, 0xF)   // row_shr:1
    DPP_ADD(v, 0x112, 0xF)   // row_shr:2
    DPP_ADD(v, 0x114, 0xF)   // row_shr:4
    DPP_ADD(v, 0x118, 0xF)   // row_shr:8
    DPP_ADD(v, 0x142, 0xA)   // row_bcast:15 -> rows 1,3
    DPP_ADD(v, 0x143, 0xC)   // row_bcast:31 -> rows 2,3
    return __int_as_float(__builtin_amdgcn_readlane(__float_as_int(v), 63));
}
__device__ __forceinline__ float wave_red_max(float v) {
    DPP_MAX(v, 0x111, 0xF)
    DPP_MAX(v, 0x112, 0xF)
    DPP_MAX(v, 0x114, 0xF)
    DPP_MAX(v, 0x118, 0xF)
    DPP_MAX(v, 0x142, 0xA)
    DPP_MAX(v, 0x143, 0xC)
    return __int_as_float(__builtin_amdgcn_readlane(__float_as_int(v), 63));
}

__global__ __launch_bounds__(256) void heur9_kernel(const float* __restrict__ boards,
                                                    const int* __restrict__ cur,
                                                    float* __restrict__ out, int B) {
    __shared__ float sD[4][NW + 1];
    const int wave = threadIdx.x >> 6;
    const int lane = threadIdx.x & 63;
    const int b = (blockIdx.x << 2) | wave;   // grid = B/4 exactly
    float* dl = sD[wave];
    const float* brd = boards + b * NB;

    // ---- Issue ALL independent global loads up front so their (cold-cache) latency
    // overlaps the window pass. cw32 rows are 32B-aligned: dwordx4 + dword each.
    const uint4 qa0 = *(const uint4*)&TAB.cw32[lane][0];
    const unsigned qa4 = TAB.cw32[lane][4];
    uint4 qb0 = make_uint4(0x8C8C8C8Cu, 0x8C8C8C8Cu, 0x8C8C8C8Cu, 0x8C8C8C8Cu);
    unsigned qb4 = 0x8C8C8C8Cu;
    if (lane < NB - 64) {
        qb0 = *(const uint4*)&TAB.cw32[lane + 64][0];
        qb4 = TAB.cw32[lane + 64][4];
    }
    const U2 m0 = TAB.m[lane];
    const U2 m1 = TAB.m[lane + 64];   // lane+64 <= 127 < 140

    const float pf = (float)cur[b];
    const float of = 3.0f - pf;
    const float v1 = brd[lane];
    const float v2 = (lane < NB - 64) ? brd[lane + 64] : -1.0f;  // -1 matches neither player

    // Occupancy bitboards via wave ballot (uniform across wave).
    const unsigned long long p_lo = __ballot(v1 == pf);
    const unsigned long long p_hi = __ballot(v2 == pf);
    const unsigned long long o_lo = __ballot(v1 == of);
    const unsigned long long o_hi = __ballot(v2 == of);
    const unsigned long long e_lo = ~(p_lo | o_lo);
    const unsigned long long e_hi = ~(p_hi | o_hi);  // only low 17 bits meaningful

    // Window pass: 3 fixed strides, one popcount pair + one 8B table load per window.
    float evp = 0.f;
    {
        const int pc = __popcll(p_lo & m0.x) + __popcll(p_hi & m0.y);
        const int oc = __popcll(o_lo & m0.x) + __popcll(o_hi & m0.y);
        const F2 tt = WT.v[(oc << 3) + pc];
        evp += tt.e;
        dl[lane] = tt.d;
    }
    {
        const int pc = __popcll(p_lo & m1.x) + __popcll(p_hi & m1.y);
        const int oc = __popcll(o_lo & m1.x) + __popcll(o_hi & m1.y);
        const F2 tt = WT.v[(oc << 3) + pc];
        evp += tt.e;
        dl[lane + 64] = tt.d;
    }
    if (lane < NW - 128) {            // lanes 0..11
        const U2 m2 = TAB.m[lane + 128];
        const int pc = __popcll(p_lo & m2.x) + __popcll(p_hi & m2.y);
        const int oc = __popcll(o_lo & m2.x) + __popcll(o_hi & m2.y);
        const F2 tt = WT.v[(oc << 3) + pc];
        evp += tt.e;
        dl[lane + 128] = tt.d;
    }
    if (lane == 0) dl[NW] = 0.f;      // dummy window for table padding

    const float ev = wave_red_sum(evp);

    // sD[wave] is private to this wave: a wave-local LDS drain replaces __syncthreads().
    // ds_reads below are memory ops, so the "memory" clobber orders them after the wait.
    asm volatile("s_waitcnt lgkmcnt(0)" ::: "memory");

    // Cell pass: gather <=20 per-window deltas; indices already in registers.
    float sd1 = dl[qa0.x & 255] + dl[(qa0.x >> 8) & 255] + dl[(qa0.x >> 16) & 255] + dl[qa0.x >> 24]
              + dl[qa0.y & 255] + dl[(qa0.y >> 8) & 255] + dl[(qa0.y >> 16) & 255] + dl[qa0.y >> 24]
              + dl[qa0.z & 255] + dl[(qa0.z >> 8) & 255] + dl[(qa0.z >> 16) & 255] + dl[qa0.z >> 24]
              + dl[qa0.w & 255] + dl[(qa0.w >> 8) & 255] + dl[(qa0.w >> 16) & 255] + dl[qa0.w >> 24]
              + dl[qa4 & 255] + dl[(qa4 >> 8) & 255] + dl[(qa4 >> 16) & 255] + dl[qa4 >> 24];
    float sd2 = 0.f;
    if (lane < NB - 64) {
        sd2 = dl[qb0.x & 255] + dl[(qb0.x >> 8) & 255] + dl[(qb0.x >> 16) & 255] + dl[qb0.x >> 24]
            + dl[qb0.y & 255] + dl[(qb0.y >> 8) & 255] + dl[(qb0.y >> 16) & 255] + dl[qb0.y >> 24]
            + dl[qb0.z & 255] + dl[(qb0.z >> 8) & 255] + dl[(qb0.z >> 16) & 255] + dl[qb0.z >> 24]
            + dl[qb0.w & 255] + dl[(qb0.w >> 8) & 255] + dl[(qb0.w >> 16) & 255] + dl[qb0.w >> 24]
            + dl[qb4 & 255] + dl[(qb4 >> 8) & 255] + dl[(qb4 >> 16) & 255] + dl[qb4 >> 24];
    }
    const bool emp1 = (e_lo >> lane) & 1ull;
    const bool emp2 = (lane < NB - 64) && ((e_hi >> lane) & 1ull);
    float l1 = emp1 ? (sd1 >= 5.0e8f ? 100000.f : ev + sd1) : -1000000.f;
    float l2 = (lane < NB - 64)
                 ? (emp2 ? (sd2 >= 5.0e8f ? 100000.f : ev + sd2) : -1000000.f)
                 : -INFINITY;
    l1 *= 0.03f; l2 *= 0.03f;

    const float m = wave_red_max(fmaxf(l1, l2));
    const float e1 = __expf(l1 - m);
    const float e2 = (lane < NB - 64) ? __expf(l2 - m) : 0.f;
    const float inv = 1.0f / wave_red_sum(e1 + e2);

    out[b * NB + lane] = e1 * inv;
    if (lane < NB - 64) out[b * NB + lane + 64] = e2 * inv;
    if (lane == 0) {
        const float v = tanhf(ev * (1.f / 3000.f));
        out[B * NB + b] = fminf(fmaxf(v, -0.95f), 0.95f);
    }
}

extern "C" void kernel_launch(void* const* d_in, const int* in_sizes, int n_in,
                              void* d_out, int out_size, void* d_ws, size_t ws_size,
                              hipStream_t stream) {
    const float* boards = (const float*)d_in[0];
    const int* cur = (const int*)d_in[1];
    float* out = (float*)d_out;
    const int B = in_sizes[0] / NB;   // 2048
    heur9_kernel<<<B / 4, 256, 0, stream>>>(boards, cur, out, B);
}

// Round 3
// 56.339 us; speedup vs baseline: 1.0318x; 1.0082x over previous
//
#include <hip/hip_runtime.h>
#include <math.h>

#define NB 81
#define NW 140
#define MARK (1 << 24)

// ---------- constexpr table machinery ----------
// 36 lines (9 horiz, 9 vert, 9 diag, 9 anti-diag), each with up to 5 windows
// (consecutive along the line). Per-line prefix sums of window deltas turn a
// cell's per-direction gather (a run of consecutive windows) into C[hi]-C[lo].

struct LineGeom { int r0, c0, dr, dc, n; };  // cells (r0+i*dr, c0+i*dc); n windows
constexpr LineGeom line_geom(int id) {
    const int d = id / 9, li = id % 9;
    if (d == 0) return LineGeom{li, 0, 0, 1, 5};
    if (d == 1) return LineGeom{0, li, 1, 0, 5};
    if (d == 2) {
        const int k = li - 4;
        const int r0 = k > 0 ? k : 0, c0 = k < 0 ? -k : 0;
        const int L = 9 - (k < 0 ? -k : k);
        return LineGeom{r0, c0, 1, 1, L - 4};
    }
    const int s = li + 4;
    const int r0 = s > 8 ? s - 8 : 0, c0 = s - r0;
    const int L = 9 - (s > 8 ? s - 8 : 8 - s);
    return LineGeom{r0, c0, 1, -1, L - 4};
}

struct alignas(16) LWin { unsigned long long lo; unsigned hi; unsigned flag; };  // flag: 0 valid, 48 dummy
struct LineTab { LWin w[36][5]; };
constexpr LineTab make_lines() {
    LineTab t{};
    for (int id = 0; id < 36; ++id) {
        const LineGeom g = line_geom(id);
        for (int k = 0; k < 5; ++k) {
            unsigned long long lo = 0; unsigned hi = 0; unsigned flag = 48;
            if (k < g.n) {
                flag = 0;
                for (int j = 0; j < 5; ++j) {
                    const int cell = (g.r0 + (k + j) * g.dr) * 9 + (g.c0 + (k + j) * g.dc);
                    if (cell < 64) lo |= 1ull << cell; else hi |= 1u << (cell - 64);
                }
            }
            t.w[id][k] = LWin{lo, hi, flag};
        }
    }
    return t;
}

// (oc,pc) -> {int delta, int ev-contribution}; entries 48..95 are zero (dummy windows:
// mask==0 gives pc=oc=0, flag adds 48 -> index 48). All values integer multiples of 5,
// win marker = 2^24; non-win cell sums <= 2e6 so int arithmetic is exact and marker
// cancellation in prefix differences is exact.
struct I2 { int d, e; };
struct WTabI { I2 v[96]; };
constexpr WTabI make_wt() {
    WTabI t{};
    int PT[6] = {0, 5, 50, 500, 5000, 100000};
    for (int oc = 0; oc < 6; ++oc)
        for (int pc = 0; pc < 6; ++pc) {
            int d = 0, e = 0;
            if (oc == 0)      { if (pc < 5) d = PT[pc + 1] - PT[pc]; e = PT[pc]; }
            else if (pc == 0) { d = PT[oc]; e = -PT[oc]; }
            if (pc == 4) d = MARK;   // win marker (empty member => oc==0 automatically)
            t.v[oc * 8 + pc] = I2{d, e};
        }
    return t;
}

// Per cell: 4 dirs x (lo_slot, hi_slot) u16 slot indices into the 36x8 prefix array.
// Direction absent (short diagonals) -> (0,0): C[0]-C[0] = 0.
struct CellIdx { unsigned short s[NB][8]; };
constexpr CellIdx make_cidx() {
    CellIdx t{};
    for (int r = 0; r < 9; ++r)
        for (int c = 0; c < 9; ++c) {
            const int cell = r * 9 + c;
            for (int d = 0; d < 4; ++d) {
                int lo = 0, hi = 0, line = -1, i = 0;
                if (d == 0)      { line = r;     i = c; }
                else if (d == 1) { line = 9 + c; i = r; }
                else if (d == 2) { const int k = r - c; if (k >= -4 && k <= 4) { line = 18 + (k + 4); i = (r < c ? r : c); } }
                else             { const int s = r + c; if (s >= 4 && s <= 12) { line = 27 + (s - 4); i = r - (s > 8 ? s - 8 : 0); } }
                if (line >= 0) {
                    const LineGeom g = line_geom(line);
                    const int jlo = (i - 4 > 0) ? i - 4 : 0;
                    const int jhi = (i < g.n - 1) ? i : g.n - 1;
                    lo = line * 8 + jlo;
                    hi = line * 8 + jhi + 1;
                }
                t.s[cell][2 * d]     = (unsigned short)lo;
                t.s[cell][2 * d + 1] = (unsigned short)hi;
            }
        }
    return t;
}

__device__ __constant__ LineTab LT = make_lines();
__device__ __constant__ WTabI  WT = make_wt();
__device__ __constant__ CellIdx CIX = make_cidx();

// ---------- DPP full-wave reductions (lane 63 -> readlane broadcast) ----------
#define DPP_ADD_F(v, ctrl, rmask)                                                            \
    v += __int_as_float(                                                                     \
        __builtin_amdgcn_update_dpp(0, __float_as_int(v), ctrl, rmask, 0xF, true));
#define DPP_MAX_F(v, ctrl, rmask)                                                            \
    {                                                                                        \
        const int _x = __builtin_amdgcn_update_dpp(__float_as_int(v), __float_as_int(v),     \
                                                   ctrl, rmask, 0xF, false);                 \
        v = fmaxf(v, __int_as_float(_x));                                                    \
    }

__device__ __forceinline__ float wave_red_sum(float v) {
    DPP_ADD_F(v, 0x111, 0xF)  DPP_ADD_F(v, 0x112, 0xF)  DPP_ADD_F(v, 0x114, 0xF)
    DPP_ADD_F(v, 0x118, 0xF)  DPP_ADD_F(v, 0x142, 0xA)  DPP_ADD_F(v, 0x143, 0xC)
    return __int_as_float(__builtin_amdgcn_readlane(__float_as_int(v), 63));
}
__device__ __forceinline__ float wave_red_max(float v) {
    DPP_MAX_F(v, 0x111, 0xF)  DPP_MAX_F(v, 0x112, 0xF)  DPP_MAX_F(v, 0x114, 0xF)
    DPP_MAX_F(v, 0x118, 0xF)  DPP_MAX_F(v, 0x142, 0xA)  DPP_MAX_F(v, 0x143, 0xC)
    return __int_as_float(__builtin_amdgcn_readlane(__float_as_int(v), 63));
}
__device__ __forceinline__ int wave_red_sum_i(int v) {
    v += __builtin_amdgcn_update_dpp(0, v, 0x111, 0xF, 0xF, true);
    v += __builtin_amdgcn_update_dpp(0, v, 0x112, 0xF, 0xF, true);
    v += __builtin_amdgcn_update_dpp(0, v, 0x114, 0xF, 0xF, true);
    v += __builtin_amdgcn_update_dpp(0, v, 0x118, 0xF, 0xF, true);
    v += __builtin_amdgcn_update_dpp(0, v, 0x142, 0xA, 0xF, true);
    v += __builtin_amdgcn_update_dpp(0, v, 0x143, 0xC, 0xF, true);
    return __builtin_amdgcn_readlane(v, 63);
}

// One line-window step: masks in a uint4 {lo_lo, lo_hi, hi, flag}.
#define WSTEP(M, Cin, Cout)                                                                  \
    {                                                                                        \
        const unsigned long long lo = M.x | ((unsigned long long)M.y << 32);                 \
        const int pc = __popcll(p_lo & lo) + __popc(ph & M.z);                               \
        const int oc = __popcll(o_lo & lo) + __popc(oh & M.z);                               \
        const I2 tt = WT.v[M.w + (oc << 3) + pc];                                            \
        evp += tt.e;                                                                         \
        Cout = Cin + (unsigned)tt.d;                                                         \
    }

__global__ __launch_bounds__(256) void heur9_kernel(const float* __restrict__ boards,
                                                    const int* __restrict__ cur,
                                                    float* __restrict__ out, int B) {
    __shared__ unsigned sC[4][320];   // per-wave: 36 lines x 8 slots (C[0..5] prefix, 2 pad)
    const int wave = threadIdx.x >> 6;
    const int lane = threadIdx.x & 63;
    const int b = (blockIdx.x << 2) | wave;   // grid = B/4 exactly
    unsigned* cw = sC[wave];
    const float* brd = boards + b * NB;

    // ---- hoist all independent (possibly cold-cache) loads to the top.
    const uint4 ci1 = *(const uint4*)&CIX.s[lane][0];
    uint4 ci2 = make_uint4(0, 0, 0, 0);
    if (lane < NB - 64) ci2 = *(const uint4*)&CIX.s[lane + 64][0];
    uint4 lt0{}, lt1{}, lt2{}, lt3{}, lt4{};
    if (lane < 36) {
        const uint4* lt = (const uint4*)&LT.w[lane][0];   // 80B contiguous per lane
        lt0 = lt[0]; lt1 = lt[1]; lt2 = lt[2]; lt3 = lt[3]; lt4 = lt[4];
    }

    const float pf = (float)cur[b];
    const float of = 3.0f - pf;
    const float v1 = brd[lane];
    const float v2 = (lane < NB - 64) ? brd[lane + 64] : -1.0f;  // matches neither player

    // Occupancy bitboards via wave ballot (uniform across wave).
    const unsigned long long p_lo = __ballot(v1 == pf);
    const unsigned long long p_hi = __ballot(v2 == pf);
    const unsigned long long o_lo = __ballot(v1 == of);
    const unsigned long long o_hi = __ballot(v2 == of);
    const unsigned long long e_lo = ~(p_lo | o_lo);
    const unsigned long long e_hi = ~(p_hi | o_hi);  // only low 17 bits meaningful

    // ---- line pass: lane = line, serial prefix over its <=5 windows (int-exact).
    int evp = 0;
    if (lane < 36) {
        const unsigned ph = (unsigned)p_hi, oh = (unsigned)o_hi;
        unsigned C0 = 0, C1, C2, C3, C4, C5;
        WSTEP(lt0, C0, C1)
        WSTEP(lt1, C1, C2)
        WSTEP(lt2, C2, C3)
        WSTEP(lt3, C3, C4)
        WSTEP(lt4, C4, C5)
        *(uint4*)(cw + lane * 8) = make_uint4(C0, C1, C2, C3);
        *(uint2*)(cw + lane * 8 + 4) = make_uint2(C4, C5);
    }
    const float ev = (float)wave_red_sum_i(evp);   // exact: |ev| <= 1.4e7 < 2^24

    // sC[wave] is wave-private: wave-local LDS drain replaces __syncthreads().
    asm volatile("s_waitcnt lgkmcnt(0)" ::: "memory");

    // ---- cell pass: 4 dirs x (C[hi]-C[lo]) = 8 LDS reads per cell.
#define RD(s) ((int)cw[(s)])
    const int s1 = RD(ci1.x >> 16) - RD(ci1.x & 0xFFFF)
                 + RD(ci1.y >> 16) - RD(ci1.y & 0xFFFF)
                 + RD(ci1.z >> 16) - RD(ci1.z & 0xFFFF)
                 + RD(ci1.w >> 16) - RD(ci1.w & 0xFFFF);
    int s2 = 0;
    if (lane < NB - 64)
        s2 = RD(ci2.x >> 16) - RD(ci2.x & 0xFFFF)
           + RD(ci2.y >> 16) - RD(ci2.y & 0xFFFF)
           + RD(ci2.z >> 16) - RD(ci2.z & 0xFFFF)
           + RD(ci2.w >> 16) - RD(ci2.w & 0xFFFF);
#undef RD

    const bool emp1 = (e_lo >> lane) & 1ull;
    const bool emp2 = (lane < NB - 64) && ((e_hi >> lane) & 1ull);
    float l1 = emp1 ? (s1 >= MARK ? 100000.f : ev + (float)s1) : -1000000.f;
    float l2 = (lane < NB - 64)
                 ? (emp2 ? (s2 >= MARK ? 100000.f : ev + (float)s2) : -1000000.f)
                 : -INFINITY;
    l1 *= 0.03f; l2 *= 0.03f;

    const float m = wave_red_max(fmaxf(l1, l2));
    const float e1 = __expf(l1 - m);
    const float e2 = (lane < NB - 64) ? __expf(l2 - m) : 0.f;
    const float inv = 1.0f / wave_red_sum(e1 + e2);

    out[b * NB + lane] = e1 * inv;
    if (lane < NB - 64) out[b * NB + lane + 64] = e2 * inv;
    if (lane == 0) {
        const float v = tanhf(ev * (1.f / 3000.f));
        out[B * NB + b] = fminf(fmaxf(v, -0.95f), 0.95f);
    }
}

extern "C" void kernel_launch(void* const* d_in, const int* in_sizes, int n_in,
                              void* d_out, int out_size, void* d_ws, size_t ws_size,
                              hipStream_t stream) {
    const float* boards = (const float*)d_in[0];
    const int* cur = (const int*)d_in[1];
    float* out = (float*)d_out;
    const int B = in_sizes[0] / NB;   // 2048
    heur9_kernel<<<B / 4, 256, 0, stream>>>(boards, cur, out, B);
}